// Round 1
// baseline (71.545 us; speedup 1.0000x reference)
//
#include <hip/hip_runtime.h>

#define B_  32
#define S_  512
#define N_  64
#define D_  64
#define ND_ 4096   // N_*D_

// qw[n,d] = (sum_e (q_embed[n,:] . Wq_w[e,:] + Wq_b[e]) * Wkv_w[e,d]) / sqrt(D)
__global__ void qw_kernel(const float* __restrict__ qe, const float* __restrict__ Wq_w,
                          const float* __restrict__ Wq_b, const float* __restrict__ Wkv_w,
                          float* __restrict__ qw) {
    const int n = blockIdx.x;   // 64 blocks
    const int t = threadIdx.x;  // 64 threads
    __shared__ float qrow[D_];
    float acc = Wq_b[t];
    const float* qen = qe + n * D_;
    const float* wqr = Wq_w + t * D_;   // Wq_w is (D,D); q = qe @ Wq_w^T -> q[n,e]=sum_d qe[n,d]*Wq_w[e,d]
#pragma unroll 8
    for (int d = 0; d < D_; ++d) acc += qen[d] * wqr[d];
    qrow[t] = acc;
    __syncthreads();
    float s = 0.f;
#pragma unroll 8
    for (int e = 0; e < D_; ++e) s += qrow[e] * Wkv_w[e * D_ + t];  // only e<D (the k half)
    qw[n * D_ + t] = s * 0.125f;  // 1/sqrt(64)
}

// One pass over x: per (b, s-chunk) block computes online-softmax partial
// (m, l, o[4096]) where o = sum_s exp(prod[s]-m) * x[b,s,:,:]
__global__ __launch_bounds__(256) void flash_partial(
    const float* __restrict__ x, const float* __restrict__ qw,
    float* __restrict__ po, float* __restrict__ pml,
    int schunks, int chunk) {
    const int blk = blockIdx.x;
    const int b   = blk / schunks;
    const int c   = blk - b * schunks;
    const int t   = threadIdx.x;     // 0..255
    const int s0  = c * chunk;

    // per-thread slice: element idx(k,j) = k*1024 + t*4 + j  (fully coalesced float4)
    float qwr[4][4];
#pragma unroll
    for (int k = 0; k < 4; ++k) {
        float4 v = *(const float4*)(qw + k * 1024 + t * 4);
        qwr[k][0] = v.x; qwr[k][1] = v.y; qwr[k][2] = v.z; qwr[k][3] = v.w;
    }

    float o[4][4] = {{0.f, 0.f, 0.f, 0.f}};
    float m = -3.0e38f, l = 0.f;

    __shared__ float red[4];

    const float* xb = x + (size_t)(b * S_ + s0) * ND_;

    for (int si = 0; si < chunk; ++si) {
        float xr[4][4];
#pragma unroll
        for (int k = 0; k < 4; ++k) {
            float4 v = *(const float4*)(xb + (size_t)si * ND_ + k * 1024 + t * 4);
            xr[k][0] = v.x; xr[k][1] = v.y; xr[k][2] = v.z; xr[k][3] = v.w;
        }
        float pd = 0.f;
#pragma unroll
        for (int k = 0; k < 4; ++k)
#pragma unroll
            for (int j = 0; j < 4; ++j)
                pd += xr[k][j] * qwr[k][j];
        // wave (64-lane) butterfly reduce
#pragma unroll
        for (int off = 32; off > 0; off >>= 1)
            pd += __shfl_xor(pd, off, 64);
        if ((t & 63) == 0) red[t >> 6] = pd;
        __syncthreads();
        const float p = red[0] + red[1] + red[2] + red[3];
        __syncthreads();

        const float mn = fmaxf(m, p);
        const float sc = __expf(m - mn);   // 0 on first iter (m=-3e38)
        const float w  = __expf(p - mn);
        l = l * sc + w;
#pragma unroll
        for (int k = 0; k < 4; ++k)
#pragma unroll
            for (int j = 0; j < 4; ++j)
                o[k][j] = o[k][j] * sc + w * xr[k][j];
        m = mn;
    }

    float* pob = po + (size_t)blk * ND_;
#pragma unroll
    for (int k = 0; k < 4; ++k) {
        float4 v = { o[k][0], o[k][1], o[k][2], o[k][3] };
        *(float4*)(pob + k * 1024 + t * 4) = v;
    }
    if (t == 0) { pml[blk * 2] = m; pml[blk * 2 + 1] = l; }
}

// Merge the schunks partials per batch: out[b,:] = sum_c exp(m_c-M)*o_c / sum_c exp(m_c-M)*l_c
__global__ __launch_bounds__(256) void combine_kernel(
    const float* __restrict__ po, const float* __restrict__ pml,
    float* __restrict__ out, int schunks) {
    const int b   = blockIdx.x >> 4;   // 16 segments of 256 cover ND_=4096
    const int seg = blockIdx.x & 15;
    const int t   = threadIdx.x;
    const int idx = seg * 256 + t;
    __shared__ float sm[64], sl[64];
    if (t < schunks) {
        sm[t] = pml[(b * schunks + t) * 2];
        sl[t] = pml[(b * schunks + t) * 2 + 1];
    }
    __syncthreads();
    float M = -3.0e38f;
    for (int c = 0; c < schunks; ++c) M = fmaxf(M, sm[c]);
    float L = 0.f, acc = 0.f;
    for (int c = 0; c < schunks; ++c) {
        const float w = __expf(sm[c] - M);
        L += w * sl[c];
        acc += w * po[(size_t)(b * schunks + c) * ND_ + idx];
    }
    out[(size_t)b * ND_ + idx] = acc / L;
}

extern "C" void kernel_launch(void* const* d_in, const int* in_sizes, int n_in,
                              void* d_out, int out_size, void* d_ws, size_t ws_size,
                              hipStream_t stream) {
    const float* x     = (const float*)d_in[0];
    const float* qe    = (const float*)d_in[1];
    const float* Wq_w  = (const float*)d_in[2];
    const float* Wq_b  = (const float*)d_in[3];
    const float* Wkv_w = (const float*)d_in[4];
    // d_in[5] = Wkv_b: only shifts prod by a per-(b,s)-uniform constant -> softmax-invariant, unused.
    float* out = (float*)d_out;

    // workspace layout: qw[ND_] | pml[B_*schunks*2] | po[B_*schunks*ND_]
    int schunks = 64;
    while (schunks > 1) {
        size_t need = ((size_t)ND_ + (size_t)B_ * schunks * 2 + (size_t)B_ * schunks * ND_) * sizeof(float);
        if (need <= ws_size) break;
        schunks >>= 1;
    }
    const int chunk = S_ / schunks;

    float* qw  = (float*)d_ws;
    float* pml = qw + ND_;
    float* po  = pml + (size_t)B_ * schunks * 2;

    qw_kernel<<<dim3(N_), dim3(D_), 0, stream>>>(qe, Wq_w, Wq_b, Wkv_w, qw);
    flash_partial<<<dim3(B_ * schunks), dim3(256), 0, stream>>>(x, qw, po, pml, schunks, chunk);
    combine_kernel<<<dim3(B_ * 16), dim3(256), 0, stream>>>(po, pml, out, schunks);
}

// Round 3
// 61.822 us; speedup vs baseline: 1.1573x; 1.1573x over previous
//
#include <hip/hip_runtime.h>

#define B_   32
#define S_   512
#define N_   64
#define D_   64
#define ND_  4096   // N_*D_
#define SCH  32     // s-chunks per batch
#define CH   16     // S_/SCH rows per chunk
#define R_   4      // rows per barrier phase

// qw[n,d] = (sum_e (q_embed[n,:] . Wq_w[e,:] + Wq_b[e]) * Wkv_w[e,d]) / sqrt(D)
__global__ void qw_kernel(const float* __restrict__ qe, const float* __restrict__ Wq_w,
                          const float* __restrict__ Wq_b, const float* __restrict__ Wkv_w,
                          float* __restrict__ qw) {
    const int n = blockIdx.x;   // 64 blocks
    const int t = threadIdx.x;  // 64 threads
    __shared__ float qrow[D_];
    float acc = Wq_b[t];
    const float* qen = qe + n * D_;
    const float* wqr = Wq_w + t * D_;   // q[n,e] = sum_d qe[n,d]*Wq_w[e,d] + b[e]
#pragma unroll 8
    for (int d = 0; d < D_; ++d) acc += qen[d] * wqr[d];
    qrow[t] = acc;
    __syncthreads();
    float s = 0.f;
#pragma unroll 8
    for (int e = 0; e < D_; ++e) s += qrow[e] * Wkv_w[e * D_ + t];  // k half only
    qw[n * D_ + t] = s * 0.125f;  // 1/sqrt(64)
}

// One pass over x. Per (b, s-chunk) block: online-softmax partial (m, l, o[4096]).
// R_=4 rows per __syncthreads phase: barriers amortized 8x vs per-row, and the
// x values stay in registers between the dot and the o-accumulate.
__global__ __launch_bounds__(256) void flash_partial(
    const float* __restrict__ x, const float* __restrict__ qw,
    float* __restrict__ po, float* __restrict__ pml) {
    const int blk  = blockIdx.x;
    const int b    = blk >> 5;        // / SCH
    const int c    = blk & (SCH - 1);
    const int t    = threadIdx.x;     // 0..255
    const int w    = t >> 6;          // wave id 0..3
    const int lane = t & 63;
    const int s0   = c * CH;

    // thread slice: element k*1024 + t*4 + j (coalesced float4 per wave)
    float4 qv[4];
#pragma unroll
    for (int k = 0; k < 4; ++k) qv[k] = *(const float4*)(qw + k * 1024 + t * 4);

    float o[4][4] = {{0.f, 0.f, 0.f, 0.f}};
    float m = -3.0e38f, l = 0.f;

    __shared__ float red[2][4][R_];   // [parity][wave][row]

    const float* xb = x + (size_t)(b * S_ + s0) * ND_ + t * 4;

    for (int ph = 0; ph < CH / R_; ++ph) {
        const int par = ph & 1;
        const float* xp = xb + (size_t)(ph * R_) * ND_;

        // load 4 rows (16 float4 loads issued back-to-back)
        float4 cur[R_][4];
#pragma unroll
        for (int r = 0; r < R_; ++r)
#pragma unroll
            for (int k = 0; k < 4; ++k)
                cur[r][k] = *(const float4*)(xp + (size_t)r * ND_ + k * 1024);

        // per-row quarter dots
        float pd[R_];
#pragma unroll
        for (int r = 0; r < R_; ++r) {
            float s = 0.f;
#pragma unroll
            for (int k = 0; k < 4; ++k)
                s += cur[r][k].x * qv[k].x + cur[r][k].y * qv[k].y +
                     cur[r][k].z * qv[k].z + cur[r][k].w * qv[k].w;
            pd[r] = s;
        }

        // 64-lane butterfly, 4 rows interleaved
#pragma unroll
        for (int off = 32; off > 0; off >>= 1)
#pragma unroll
            for (int r = 0; r < R_; ++r)
                pd[r] += __shfl_xor(pd[r], off, 64);

        if (lane == 0) {
#pragma unroll
            for (int r = 0; r < R_; ++r) red[par][w][r] = pd[r];
        }
        __syncthreads();   // full fence semantics - safe cross-wave visibility

        // batched online-softmax update (single rescale of o)
        float p[R_];
#pragma unroll
        for (int r = 0; r < R_; ++r)
            p[r] = red[par][0][r] + red[par][1][r] + red[par][2][r] + red[par][3][r];

        float mb = fmaxf(fmaxf(p[0], p[1]), fmaxf(p[2], p[3]));
        const float mn = fmaxf(m, mb);
        const float sc = __expf(m - mn);    // 0 on first phase
        float wt[R_], ws = 0.f;
#pragma unroll
        for (int r = 0; r < R_; ++r) { wt[r] = __expf(p[r] - mn); ws += wt[r]; }
        l = l * sc + ws;
#pragma unroll
        for (int k = 0; k < 4; ++k) {
#pragma unroll
            for (int j = 0; j < 4; ++j) {
                float* oe = &o[k][j];
                float acc = *oe * sc;
                acc += wt[0] * (&cur[0][k].x)[j];
                acc += wt[1] * (&cur[1][k].x)[j];
                acc += wt[2] * (&cur[2][k].x)[j];
                acc += wt[3] * (&cur[3][k].x)[j];
                *oe = acc;
            }
        }
        m = mn;
    }

    float* pob = po + (size_t)blk * ND_ + t * 4;
#pragma unroll
    for (int k = 0; k < 4; ++k) {
        float4 v = { o[k][0], o[k][1], o[k][2], o[k][3] };
        *(float4*)(pob + k * 1024) = v;
    }
    if (t == 0) { pml[blk * 2] = m; pml[blk * 2 + 1] = l; }
}

// out[b,:] = sum_c exp(m_c-M)*o_c / sum_c exp(m_c-M)*l_c
__global__ __launch_bounds__(256) void combine_kernel(
    const float* __restrict__ po, const float* __restrict__ pml,
    float* __restrict__ out) {
    const int b   = blockIdx.x >> 4;   // 16 segments of 256 cover ND_
    const int seg = blockIdx.x & 15;
    const int t   = threadIdx.x;
    const int idx = seg * 256 + t;
    __shared__ float sm[SCH], sl[SCH];
    if (t < SCH) {
        sm[t] = pml[(b * SCH + t) * 2];
        sl[t] = pml[(b * SCH + t) * 2 + 1];
    }
    __syncthreads();
    float M = -3.0e38f;
#pragma unroll
    for (int c = 0; c < SCH; ++c) M = fmaxf(M, sm[c]);
    float L = 0.f, acc = 0.f;
    for (int c = 0; c < SCH; ++c) {
        const float wc = __expf(sm[c] - M);
        L += wc * sl[c];
        acc += wc * po[(size_t)(b * SCH + c) * ND_ + idx];
    }
    out[(size_t)b * ND_ + idx] = acc / L;
}

extern "C" void kernel_launch(void* const* d_in, const int* in_sizes, int n_in,
                              void* d_out, int out_size, void* d_ws, size_t ws_size,
                              hipStream_t stream) {
    const float* x     = (const float*)d_in[0];
    const float* qe    = (const float*)d_in[1];
    const float* Wq_w  = (const float*)d_in[2];
    const float* Wq_b  = (const float*)d_in[3];
    const float* Wkv_w = (const float*)d_in[4];
    // d_in[5] = Wkv_b: shifts prod by a per-(b,s)-uniform constant -> softmax-invariant.
    float* out = (float*)d_out;

    // ws layout: qw[ND_] | pml[B_*SCH*2] | po[B_*SCH*ND_]  (~16.9 MB)
    float* qw  = (float*)d_ws;
    float* pml = qw + ND_;
    float* po  = pml + (size_t)B_ * SCH * 2;

    qw_kernel<<<dim3(N_), dim3(D_), 0, stream>>>(qe, Wq_w, Wq_b, Wkv_w, qw);
    flash_partial<<<dim3(B_ * SCH), dim3(256), 0, stream>>>(x, qw, po, pml);
    combine_kernel<<<dim3(B_ * 16), dim3(256), 0, stream>>>(po, pml, out);
}

// Round 4
// 57.654 us; speedup vs baseline: 1.2409x; 1.0723x over previous
//
#include <hip/hip_runtime.h>

#define B_   32
#define S_   512
#define ND_  4096   // N*D = 64*64
#define SCH  16     // s-chunks per batch
#define CH   32     // rows per block chunk (S_/SCH)
#define RW   8      // rows per wave (CH/4)

// qw[n,d] = (sum_e (q_embed[n,:] . Wq_w[e,:] + Wq_b[e]) * Wkv_w[e,d]) / sqrt(D)
__global__ void qw_kernel(const float* __restrict__ qe, const float* __restrict__ Wq_w,
                          const float* __restrict__ Wq_b, const float* __restrict__ Wkv_w,
                          float* __restrict__ qw) {
    const int n = blockIdx.x;   // 64 blocks
    const int t = threadIdx.x;  // 64 threads
    __shared__ float qrow[64];
    float acc = Wq_b[t];
    const float* qen = qe + n * 64;
    const float* wqr = Wq_w + t * 64;   // q[n,e] = sum_d qe[n,d]*Wq_w[e,d] + b[e]
#pragma unroll 8
    for (int d = 0; d < 64; ++d) acc += qen[d] * wqr[d];
    qrow[t] = acc;
    __syncthreads();
    float s = 0.f;
#pragma unroll 8
    for (int e = 0; e < 64; ++e) s += qrow[e] * Wkv_w[e * 64 + t];  // k half only
    qw[n * 64 + t] = s * 0.125f;  // 1/sqrt(64)
}

// One pass over x. Each WAVE owns whole s-rows: lane l holds float4 j*64+l of the
// 4096-elem row, dot = 64-lane butterfly. No barriers / no LDS in the main loop;
// per-block merge of the 4 wave partials happens once at the end.
__global__ __launch_bounds__(256, 2) void flash_partial(
    const float* __restrict__ x, const float* __restrict__ qw,
    float* __restrict__ po, float* __restrict__ pml) {
    const int blk = blockIdx.x;
    const int b   = blk >> 4;        // / SCH
    const int c   = blk & (SCH - 1);
    const int t   = threadIdx.x;
    const int w   = t >> 6;          // wave 0..3
    const int l   = t & 63;

    const float4* qw4 = (const float4*)qw;
    float4 qv[16];
#pragma unroll
    for (int j = 0; j < 16; ++j) qv[j] = qw4[j * 64 + l];

    float4 o[16];
#pragma unroll
    for (int j = 0; j < 16; ++j) o[j] = make_float4(0.f, 0.f, 0.f, 0.f);
    float m = -3.0e38f, lsum = 0.f;

    const int s0 = c * CH + w * RW;
    const float4* xb = (const float4*)(x) + (size_t)(b * S_ + s0) * 1024;

    for (int r = 0; r < RW; ++r) {
        const float4* xr = xb + (size_t)r * 1024;
        float4 cur[16];
#pragma unroll
        for (int j = 0; j < 16; ++j) cur[j] = xr[j * 64 + l];

        float pd = 0.f;
#pragma unroll
        for (int j = 0; j < 16; ++j)
            pd += cur[j].x * qv[j].x + cur[j].y * qv[j].y +
                  cur[j].z * qv[j].z + cur[j].w * qv[j].w;
#pragma unroll
        for (int off = 32; off > 0; off >>= 1)
            pd += __shfl_xor(pd, off, 64);

        const float mn = fmaxf(m, pd);
        const float sc = __expf(m - mn);    // 0 on first row
        const float wt = __expf(pd - mn);
        lsum = lsum * sc + wt;
#pragma unroll
        for (int j = 0; j < 16; ++j) {
            o[j].x = o[j].x * sc + wt * cur[j].x;
            o[j].y = o[j].y * sc + wt * cur[j].y;
            o[j].z = o[j].z * sc + wt * cur[j].z;
            o[j].w = o[j].w * sc + wt * cur[j].w;
        }
        m = mn;
    }

    // ---- merge 4 wave partials (once per block) ----
    __shared__ float  sml[4][2];
    __shared__ float4 obuf[1024];   // 16 KB
    if (l == 0) { sml[w][0] = m; sml[w][1] = lsum; }
    __syncthreads();
    const float M = fmaxf(fmaxf(sml[0][0], sml[1][0]), fmaxf(sml[2][0], sml[3][0]));
    float L = 0.f;
#pragma unroll
    for (int ww = 0; ww < 4; ++ww) L += __expf(sml[ww][0] - M) * sml[ww][1];
    const float wk = __expf(sml[w][0] - M);

    if (w == 0) {
#pragma unroll
        for (int j = 0; j < 16; ++j) {
            float4 v = { wk * o[j].x, wk * o[j].y, wk * o[j].z, wk * o[j].w };
            obuf[j * 64 + l] = v;
        }
    }
    __syncthreads();
#pragma unroll
    for (int ww = 1; ww < 4; ++ww) {
        if (w == ww) {
#pragma unroll
            for (int j = 0; j < 16; ++j) {
                float4 v = obuf[j * 64 + l];
                v.x += wk * o[j].x; v.y += wk * o[j].y;
                v.z += wk * o[j].z; v.w += wk * o[j].w;
                obuf[j * 64 + l] = v;
            }
        }
        __syncthreads();
    }

    float4* pob = (float4*)(po) + (size_t)blk * 1024;
#pragma unroll
    for (int jj = 0; jj < 4; ++jj) {
        const int j = w * 4 + jj;
        pob[j * 64 + l] = obuf[j * 64 + l];
    }
    if (t == 0) { pml[blk * 2] = M; pml[blk * 2 + 1] = L; }
}

// out[b,:] = sum_c exp(m_c-M)*o_c / sum_c exp(m_c-M)*l_c
__global__ __launch_bounds__(256) void combine_kernel(
    const float* __restrict__ po, const float* __restrict__ pml,
    float* __restrict__ out) {
    const int b   = blockIdx.x >> 4;   // 16 segments of 256 cover ND_
    const int seg = blockIdx.x & 15;
    const int t   = threadIdx.x;
    const int idx = seg * 256 + t;
    __shared__ float sm[SCH], sl[SCH];
    if (t < SCH) {
        sm[t] = pml[(b * SCH + t) * 2];
        sl[t] = pml[(b * SCH + t) * 2 + 1];
    }
    __syncthreads();
    float M = -3.0e38f;
#pragma unroll
    for (int c = 0; c < SCH; ++c) M = fmaxf(M, sm[c]);
    float L = 0.f, acc = 0.f;
#pragma unroll
    for (int c = 0; c < SCH; ++c) {
        const float wc = __expf(sm[c] - M);
        L += wc * sl[c];
        acc += wc * po[(size_t)(b * SCH + c) * ND_ + idx];
    }
    out[(size_t)b * ND_ + idx] = acc / L;
}

extern "C" void kernel_launch(void* const* d_in, const int* in_sizes, int n_in,
                              void* d_out, int out_size, void* d_ws, size_t ws_size,
                              hipStream_t stream) {
    const float* x     = (const float*)d_in[0];
    const float* qe    = (const float*)d_in[1];
    const float* Wq_w  = (const float*)d_in[2];
    const float* Wq_b  = (const float*)d_in[3];
    const float* Wkv_w = (const float*)d_in[4];
    // d_in[5] = Wkv_b: shifts prod by a per-(b,s)-uniform constant -> softmax-invariant.
    float* out = (float*)d_out;

    // ws layout: qw[ND_] | pml[B_*SCH*2] | po[B_*SCH*ND_]  (~8.5 MB)
    float* qw  = (float*)d_ws;
    float* pml = qw + ND_;
    float* po  = pml + (size_t)B_ * SCH * 2;

    qw_kernel<<<dim3(64), dim3(64), 0, stream>>>(qe, Wq_w, Wq_b, Wkv_w, qw);
    flash_partial<<<dim3(B_ * SCH), dim3(256), 0, stream>>>(x, qw, po, pml);
    combine_kernel<<<dim3(B_ * 16), dim3(256), 0, stream>>>(po, pml, out);
}